// Round 1
// baseline (1012.046 us; speedup 1.0000x reference)
//
#include <hip/hip_runtime.h>

// TopK(256) + ReLU + scatter-back, rows of 16384 fp32, 8192 rows.
// One block per row, 512 threads x 32 values each, all in registers.
// Exact 256th-largest via 4-round MSB radix select on monotonic u32 keys;
// ties at the boundary resolved lower-index-first (jax.lax.top_k semantics).
//
// vs previous version (1024thr x 16, per-wave hist):
//  - 512-thread blocks -> 4 blocks/CU resident (was 2): select-phase barrier
//    bubbles of one block overlap other blocks' memory phases.
//  - histogram privatized per 16-lane group (4 copies/wave) with stride-257
//    bank stagger: Gaussian data concentrates ~28% of keys in one top-byte
//    bin (0xBF / 0x40), which made wave-wide ds_add ~18-way same-address
//    serialized. Quarter-wave copies + stagger cut that to ~4-5-way on
//    distinct banks.

#define ROWS 8192
#define COLS 16384
#define TOPK 256
#define NT   512
#define VPT  32
#define NW   (NT / 64)        // 8 waves per block
#define NCPW 4                // histogram copies per wave (per 16-lane group)
#define NHIST (NW * NCPW)     // 32 copies
#define HSTRIDE 257           // copy c, bin b -> bank (b + c) % 32

// monotonic key: descending float order == descending unsigned order
__device__ __forceinline__ unsigned f2k(float f) {
    unsigned b = __float_as_uint(f);
    return (b & 0x80000000u) ? ~b : (b | 0x80000000u);
}

// key -> relu(float): negative floats map to keys < 0x80000000 -> relu = 0
__device__ __forceinline__ float k2relu(unsigned k) {
    return (k & 0x80000000u) ? __uint_as_float(k & 0x7FFFFFFFu) : 0.0f;
}

__global__ __launch_bounds__(NT, 8) void topk_relu_scatter(
        const float* __restrict__ x, float* __restrict__ out) {
    __shared__ unsigned hist[NHIST * HSTRIDE];   // staggered privatized hists
    __shared__ unsigned summed[256];
    __shared__ unsigned warp_sums[NW];
    __shared__ unsigned s_b, s_want;

    const int tid  = threadIdx.x;
    const int lane = tid & 63;
    const int wid  = tid >> 6;
    const size_t row = blockIdx.x;

    // quarter-wave private histogram copy
    unsigned* __restrict__ myhist = &hist[(unsigned)((wid << 2) | (lane >> 4)) * HSTRIDE];

    const float4* __restrict__ xv =
        (const float4*)(x + row * (size_t)COLS) + (size_t)tid * (VPT / 4);

    unsigned keys[VPT];
    #pragma unroll
    for (int s = 0; s < VPT / 4; ++s) {
        float4 f = xv[s];
        keys[4 * s + 0] = f2k(f.x);
        keys[4 * s + 1] = f2k(f.y);
        keys[4 * s + 2] = f2k(f.z);
        keys[4 * s + 3] = f2k(f.w);
    }

    // ---- 4-round MSB-first radix select (8 bits / round) ----
    unsigned prefix = 0, mask = 0, want = TOPK;

    #pragma unroll
    for (int d = 0; d < 4; ++d) {
        const int shift = 24 - 8 * d;

        // zero all histogram bins (pad words never touched):
        // NHIST*256 = 8192 words, exactly 16 per thread, conflict-free
        #pragma unroll
        for (int i = 0; i < (NHIST * 256) / NT; ++i) {
            int idx = tid + i * NT;
            hist[(idx >> 8) * HSTRIDE + (idx & 255)] = 0;
        }
        __syncthreads();

        // accumulate digits of keys matching current prefix
        #pragma unroll
        for (int v = 0; v < VPT; ++v) {
            unsigned k = keys[v];
            if ((k & mask) == prefix)
                atomicAdd(&myhist[(k >> shift) & 0xFFu], 1u);
        }
        __syncthreads();

        // reduce privatized copies (threads 0..255; stride-257 -> no bank dup)
        if (tid < 256) {
            unsigned s = 0;
            #pragma unroll
            for (int c = 0; c < NHIST; ++c) s += hist[c * HSTRIDE + tid];
            summed[tid] = s;
        }
        __syncthreads();

        // wave 0: suffix-scan over 256 bins, pick bin of the want-th largest
        if (tid < 64) {
            unsigned c0 = summed[4 * lane + 0];
            unsigned c1 = summed[4 * lane + 1];
            unsigned c2 = summed[4 * lane + 2];
            unsigned c3 = summed[4 * lane + 3];
            unsigned s = c0 + c1 + c2 + c3;    // this lane's 4 bins
            #pragma unroll
            for (int off = 1; off < 64; off <<= 1) {
                unsigned o = __shfl_down(s, off);
                if (lane + off < 64) s += o;   // s = S(4*lane) suffix sum
            }
            unsigned sn = __shfl_down(s, 1);   // S(4*(lane+1))
            if (lane == 63) sn = 0;
            if (s >= want && sn < want) {      // exactly one lane
                unsigned S1 = s - c0;          // S(4L+1)
                unsigned S2 = S1 - c1;         // S(4L+2)
                unsigned S3 = S2 - c2;         // S(4L+3)
                unsigned b, wn;
                if (S3 >= want)      { b = 4u * lane + 3u; wn = want - sn; }
                else if (S2 >= want) { b = 4u * lane + 2u; wn = want - S3; }
                else if (S1 >= want) { b = 4u * lane + 1u; wn = want - S2; }
                else                 { b = 4u * lane + 0u; wn = want - S1; }
                s_b = b; s_want = wn;
            }
        }
        __syncthreads();
        unsigned b = s_b;
        want = s_want;
        prefix |= b << shift;
        mask   |= 0xFFu << shift;
    }

    const unsigned tkey = prefix;  // key of the 256th-largest value
    const unsigned r    = want;    // how many key==tkey elements to include

    // ---- exact tie ranks: exclusive scan of per-thread equal counts ----
    unsigned eq = 0;
    #pragma unroll
    for (int v = 0; v < VPT; ++v) eq += (keys[v] == tkey) ? 1u : 0u;

    unsigned sc = eq;
    #pragma unroll
    for (int off = 1; off < 64; off <<= 1) {
        unsigned o = __shfl_up(sc, off);
        if (lane >= off) sc += o;
    }
    if (lane == 63) warp_sums[wid] = sc;  // wave total
    __syncthreads();
    unsigned base = sc - eq;              // exclusive within wave
    for (int w = 0; w < wid; ++w) base += warp_sums[w];

    // ---- write output ----
    float4* __restrict__ ov =
        (float4*)(out + row * (size_t)COLS) + (size_t)tid * (VPT / 4);
    #pragma unroll
    for (int s = 0; s < VPT / 4; ++s) {
        float4 o;
        float* op = (float*)&o;
        #pragma unroll
        for (int l = 0; l < 4; ++l) {
            unsigned k = keys[4 * s + l];
            float val = 0.0f;
            if (k > tkey) {
                val = k2relu(k);
            } else if (k == tkey) {
                if (base < r) val = k2relu(k);
                ++base;   // lower-index-first tie order
            }
            op[l] = val;
        }
        ov[s] = o;
    }
}

extern "C" void kernel_launch(void* const* d_in, const int* in_sizes, int n_in,
                              void* d_out, int out_size, void* d_ws, size_t ws_size,
                              hipStream_t stream) {
    const float* x = (const float*)d_in[0];
    float* out = (float*)d_out;
    topk_relu_scatter<<<ROWS, NT, 0, stream>>>(x, out);
}

// Round 2
// 890.022 us; speedup vs baseline: 1.1371x; 1.1371x over previous
//
#include <hip/hip_runtime.h>

// TopK(256) + ReLU + scatter-back, rows of 16384 fp32, 8192 rows.
// One block per row, 1024 threads x 16 values each, all in registers.
// Exact 256th-largest via 4-round MSB radix select on monotonic u32 keys;
// ties at the boundary resolved lower-index-first (jax.lax.top_k semantics).
//
// vs previous versions:
//  - Round-1 lesson: LDS ds_add cost is ~flat per wave-instruction regardless
//    of address spread (privatization/stagger didn't move the conflict
//    counter). So this version cuts the NUMBER of participating atomic lanes
//    instead: a 2-rung popcount prefilter finds a lower bound L with
//    count(keys >= L) >= 256 (for N(0,1) rows, L = key(2.0) keeps ~373 of
//    16384 candidates). All radix rounds gate on k >= L. This is EXACT:
//    the 256th largest of the >=L subset is the 256th largest overall, and
//    every rank/tie computation stays within the subset (tkey >= L).
//    If the ladder fails (adversarial data), L=0 reproduces the full select.
//  - Single shared 256-bin histogram (atomics are now rare): deletes the
//    32-copy zeroing (16 stores/thread/round) and the copy-reduce phase.
//  - Back to NT=1024/VPT=16: 28 VGPR, no spills (round-1's VPT=32 @ 64-VGPR
//    cap spilled keys -> +250 MB scratch writes).

#define ROWS 8192
#define COLS 16384
#define TOPK 256
#define NT   1024
#define VPT  16
#define NW   (NT / 64)   // 16 waves per block

// monotonic key: descending float order == descending unsigned order
__device__ __forceinline__ unsigned f2k(float f) {
    unsigned b = __float_as_uint(f);
    return (b & 0x80000000u) ? ~b : (b | 0x80000000u);
}

// key -> relu(float): negative floats map to keys < 0x80000000 -> relu = 0
__device__ __forceinline__ float k2relu(unsigned k) {
    return (k & 0x80000000u) ? __uint_as_float(k & 0x7FFFFFFFu) : 0.0f;
}

#define KEY_2_0 0xC0000000u   // f2k(2.0f)
#define KEY_1_0 0xBF800000u   // f2k(1.0f)

__global__ __launch_bounds__(NT) void topk_relu_scatter(
        const float* __restrict__ x, float* __restrict__ out) {
    __shared__ __align__(16) unsigned hist[256];
    __shared__ unsigned warp_sums[NW];
    __shared__ unsigned s_b, s_want, s_L;

    const int tid  = threadIdx.x;
    const int lane = tid & 63;
    const int wid  = tid >> 6;
    const size_t row = blockIdx.x;

    const float4* __restrict__ xv =
        (const float4*)(x + row * (size_t)COLS) + (size_t)tid * (VPT / 4);

    unsigned keys[VPT];
    #pragma unroll
    for (int s = 0; s < VPT / 4; ++s) {
        float4 f = xv[s];
        keys[4 * s + 0] = f2k(f.x);
        keys[4 * s + 1] = f2k(f.y);
        keys[4 * s + 2] = f2k(f.z);
        keys[4 * s + 3] = f2k(f.w);
    }

    // ---- prefilter: find L with count(keys >= L) >= TOPK ----
    // packed: hi 16 bits = count(>= 2.0 key), lo 16 bits = count(>= 1.0 key)
    unsigned pc = 0;
    #pragma unroll
    for (int v = 0; v < VPT; ++v) {
        pc += (keys[v] >= KEY_2_0) ? 0x10001u
            : (keys[v] >= KEY_1_0) ? 1u : 0u;
    }
    #pragma unroll
    for (int off = 1; off < 64; off <<= 1)
        pc += __shfl_xor(pc, off);
    if (lane == 0) warp_sums[wid] = pc;
    __syncthreads();
    if (tid == 0) {
        unsigned t = 0;
        #pragma unroll
        for (int w = 0; w < NW; ++w) t += warp_sums[w];
        unsigned L = 0;
        if ((t >> 16) >= TOPK)           L = KEY_2_0;
        else if ((t & 0xFFFFu) >= TOPK)  L = KEY_1_0;
        s_L = L;
    }
    __syncthreads();
    const unsigned L = s_L;

    // ---- 4-round MSB-first radix select (8 bits / round), gated to k>=L ----
    unsigned prefix = 0, mask = 0, want = TOPK;

    #pragma unroll
    for (int d = 0; d < 4; ++d) {
        const int shift = 24 - 8 * d;

        if (tid < 256) hist[tid] = 0;
        __syncthreads();

        // accumulate digits of candidate keys matching current prefix
        #pragma unroll
        for (int v = 0; v < VPT; ++v) {
            unsigned k = keys[v];
            if (k >= L && (k & mask) == prefix)
                atomicAdd(&hist[(k >> shift) & 0xFFu], 1u);
        }
        __syncthreads();

        // wave 0: suffix-scan over 256 bins, pick bin of the want-th largest
        if (tid < 64) {
            uint4 cc = *(const uint4*)&hist[4 * lane];
            unsigned c0 = cc.x, c1 = cc.y, c2 = cc.z, c3 = cc.w;
            unsigned s = c0 + c1 + c2 + c3;    // this lane's 4 bins
            #pragma unroll
            for (int off = 1; off < 64; off <<= 1) {
                unsigned o = __shfl_down(s, off);
                if (lane + off < 64) s += o;   // s = S(4*lane) suffix sum
            }
            unsigned sn = __shfl_down(s, 1);   // S(4*(lane+1))
            if (lane == 63) sn = 0;
            if (s >= want && sn < want) {      // exactly one lane
                unsigned S1 = s - c0;          // S(4L+1)
                unsigned S2 = S1 - c1;         // S(4L+2)
                unsigned S3 = S2 - c2;         // S(4L+3)
                unsigned b, wn;
                if (S3 >= want)      { b = 4u * lane + 3u; wn = want - sn; }
                else if (S2 >= want) { b = 4u * lane + 2u; wn = want - S3; }
                else if (S1 >= want) { b = 4u * lane + 1u; wn = want - S2; }
                else                 { b = 4u * lane + 0u; wn = want - S1; }
                s_b = b; s_want = wn;
            }
        }
        __syncthreads();
        unsigned b = s_b;
        want = s_want;
        prefix |= b << shift;
        mask   |= 0xFFu << shift;
    }

    const unsigned tkey = prefix;  // key of the 256th-largest value
    const unsigned r    = want;    // how many key==tkey elements to include

    // ---- exact tie ranks: exclusive scan of per-thread equal counts ----
    unsigned eq = 0;
    #pragma unroll
    for (int v = 0; v < VPT; ++v) eq += (keys[v] == tkey) ? 1u : 0u;

    unsigned sc = eq;
    #pragma unroll
    for (int off = 1; off < 64; off <<= 1) {
        unsigned o = __shfl_up(sc, off);
        if (lane >= off) sc += o;
    }
    if (lane == 63) warp_sums[wid] = sc;  // wave total
    __syncthreads();
    unsigned base = sc - eq;              // exclusive within wave
    for (int w = 0; w < wid; ++w) base += warp_sums[w];

    // ---- write output ----
    float4* __restrict__ ov =
        (float4*)(out + row * (size_t)COLS) + (size_t)tid * (VPT / 4);
    #pragma unroll
    for (int s = 0; s < VPT / 4; ++s) {
        float4 o;
        float* op = (float*)&o;
        #pragma unroll
        for (int l = 0; l < 4; ++l) {
            unsigned k = keys[4 * s + l];
            float val = 0.0f;
            if (k > tkey) {
                val = k2relu(k);
            } else if (k == tkey) {
                if (base < r) val = k2relu(k);
                ++base;   // lower-index-first tie order
            }
            op[l] = val;
        }
        ov[s] = o;
    }
}

extern "C" void kernel_launch(void* const* d_in, const int* in_sizes, int n_in,
                              void* d_out, int out_size, void* d_ws, size_t ws_size,
                              hipStream_t stream) {
    const float* x = (const float*)d_in[0];
    float* out = (float*)d_out;
    topk_relu_scatter<<<ROWS, NT, 0, stream>>>(x, out);
}